// Round 2
// baseline (124.549 us; speedup 1.0000x reference)
//
#include <hip/hip_runtime.h>

// HadamardProj: the reference's fwht butterflies pair bit-0 every step with no
// stride change, so 2 steps = 2*I; 10 steps = 32*I; the d^-0.5 = 1/32 scaling
// cancels it. fwht == identity, hence:
//   out[b,s,d] = x[b,s,d] * scales[0][d]*scales[1][d]*...*scales[4][d]
// Pure streaming elementwise multiply: 64 MiB in + 64 MiB out => ~21 us floor.
//
// Non-temporal loads/stores (read-once / write-once data, no reuse) + explicit
// 8-deep load batch for memory-level parallelism. The nt builtins require a
// native clang vector type, not HIP_vector_type — hence the ext_vector alias.

#define D_DIM 1024
#define D4 (D_DIM / 4)   // 256 float4 per row

typedef float f4 __attribute__((ext_vector_type(4)));

__global__ __launch_bounds__(256) void hadamard_proj_kernel(
    const f4* __restrict__ x,
    const float* __restrict__ scales,
    f4* __restrict__ out,
    int n4, int n_scales)
{
    const int tid    = blockIdx.x * blockDim.x + threadIdx.x;
    const int stride = gridDim.x * blockDim.x;   // 524288: multiple of D4, so
                                                 // d4 is invariant per thread
    const int d4 = tid & (D4 - 1);

    // Combined scale for this thread's fixed column group (registers, once).
    const f4* s4 = (const f4*)scales;
    f4 cs = s4[d4];
    #pragma unroll
    for (int i = 1; i < 5; ++i) {
        if (i < n_scales) {
            cs *= s4[i * D4 + d4];
        }
    }

    int i = tid;

    // Main loop: 8 nt-loads issued back-to-back (8 outstanding vmem ops per
    // thread), then 8 scaled nt-stores. Exact fit for the bench launch
    // (n4 = 4,194,304 = 8 * 2048 * 256).
    for (; i + 7 * stride < n4; i += 8 * stride) {
        f4 v0 = __builtin_nontemporal_load(&x[i + 0 * stride]);
        f4 v1 = __builtin_nontemporal_load(&x[i + 1 * stride]);
        f4 v2 = __builtin_nontemporal_load(&x[i + 2 * stride]);
        f4 v3 = __builtin_nontemporal_load(&x[i + 3 * stride]);
        f4 v4 = __builtin_nontemporal_load(&x[i + 4 * stride]);
        f4 v5 = __builtin_nontemporal_load(&x[i + 5 * stride]);
        f4 v6 = __builtin_nontemporal_load(&x[i + 6 * stride]);
        f4 v7 = __builtin_nontemporal_load(&x[i + 7 * stride]);

        v0 *= cs; v1 *= cs; v2 *= cs; v3 *= cs;
        v4 *= cs; v5 *= cs; v6 *= cs; v7 *= cs;

        __builtin_nontemporal_store(v0, &out[i + 0 * stride]);
        __builtin_nontemporal_store(v1, &out[i + 1 * stride]);
        __builtin_nontemporal_store(v2, &out[i + 2 * stride]);
        __builtin_nontemporal_store(v3, &out[i + 3 * stride]);
        __builtin_nontemporal_store(v4, &out[i + 4 * stride]);
        __builtin_nontemporal_store(v5, &out[i + 5 * stride]);
        __builtin_nontemporal_store(v6, &out[i + 6 * stride]);
        __builtin_nontemporal_store(v7, &out[i + 7 * stride]);
    }

    // Generic tail (not exercised by the bench shape).
    for (; i < n4; i += stride) {
        f4 xv = __builtin_nontemporal_load(&x[i]);
        f4 o = xv * cs;
        __builtin_nontemporal_store(o, &out[i]);
    }
}

extern "C" void kernel_launch(void* const* d_in, const int* in_sizes, int n_in,
                              void* d_out, int out_size, void* d_ws, size_t ws_size,
                              hipStream_t stream) {
    const float* x      = (const float*)d_in[0];
    const float* scales = (const float*)d_in[1];
    float*       out    = (float*)d_out;

    const int n4       = out_size / 4;            // 4,194,304 float4s
    const int n_scales = in_sizes[1] / D_DIM;     // 5

    const int block = 256;
    const int grid  = 2048;  // 8 blocks/CU on 256 CUs; 8 batched iters/thread

    hadamard_proj_kernel<<<grid, block, 0, stream>>>(
        (const f4*)x, scales, (f4*)out, n4, n_scales);
}

// Round 4
// 114.090 us; speedup vs baseline: 1.0917x; 1.0917x over previous
//
#include <hip/hip_runtime.h>

// HadamardProj: the reference's fwht butterflies pair bit-0 every step with no
// stride change, so 2 steps = 2*I; 10 steps = 32*I; the d^-0.5 = 1/32 scaling
// cancels it. fwht == identity, hence:
//   out[b,s,d] = x[b,s,d] * scales[0][d]*scales[1][d]*...*scales[4][d]
// Pure streaming elementwise multiply: 64 MiB in + 64 MiB out => ~21 us floor.
//
// Known-good configuration (harness-verified 112.2 us in R0): plain cached
// float4 grid-stride loop. nt-load/store variant (R1) regressed ~12 us —
// on MI355X the default cached path IS the fast streaming path.
// R3's post-timing-divergence failure was a harness flake (identical source
// passed R0; kernel is pure/deterministic; run showed 844 s npz push anomaly).

#define D_DIM 1024
#define D4 (D_DIM / 4)   // 256 float4 per row

__global__ __launch_bounds__(256) void hadamard_proj_kernel(
    const float4* __restrict__ x,
    const float*  __restrict__ scales,
    float4*       __restrict__ out,
    int n4, int n_scales)
{
    const int tid    = blockIdx.x * blockDim.x + threadIdx.x;
    const int stride = gridDim.x * blockDim.x;   // 524288: multiple of D4, so
                                                 // d4 is invariant per thread
    const int d4 = tid & (D4 - 1);

    // Combined scale for this thread's fixed column group (registers, once).
    const float4* s4 = (const float4*)scales;
    float4 cs = s4[d4];
    #pragma unroll
    for (int i = 1; i < 5; ++i) {
        if (i < n_scales) {
            float4 s = s4[i * D4 + d4];
            cs.x *= s.x; cs.y *= s.y; cs.z *= s.z; cs.w *= s.w;
        }
    }

    for (int i = tid; i < n4; i += stride) {
        float4 xv = x[i];
        float4 o;
        o.x = xv.x * cs.x;
        o.y = xv.y * cs.y;
        o.z = xv.z * cs.z;
        o.w = xv.w * cs.w;
        out[i] = o;
    }
}

extern "C" void kernel_launch(void* const* d_in, const int* in_sizes, int n_in,
                              void* d_out, int out_size, void* d_ws, size_t ws_size,
                              hipStream_t stream) {
    const float* x      = (const float*)d_in[0];
    const float* scales = (const float*)d_in[1];
    float*       out    = (float*)d_out;

    const int n4       = out_size / 4;            // 4,194,304 float4s
    const int n_scales = in_sizes[1] / D_DIM;     // 5

    const int block = 256;
    const int grid  = 2048;  // 8 blocks/CU on 256 CUs; 8 iterations/thread

    hadamard_proj_kernel<<<grid, block, 0, stream>>>(
        (const float4*)x, scales, (float4*)out, n4, n_scales);
}